// Round 9
// baseline (208.917 us; speedup 1.0000x reference)
//
#include <hip/hip_runtime.h>
#include <math.h>

#define B_    2
#define N_    2048
#define C_    768
#define H_    12
#define HD_   64
#define NROWS (B_*N_)      // 4096
#define QKVC  (3*C_)       // 2304
#define EPSV  1e-6f
#define SCALE 0.125f       // 1/sqrt(HD)
#define LOG2E 1.44269504088896f
#define SMAX  12.0f        // static softmax max: logit*log2e <= 8*1.443+eps < 12

typedef unsigned short u16;
typedef short bf16x8 __attribute__((ext_vector_type(8)));   // 8 bf16 = 4 VGPRs
typedef float f32x4  __attribute__((ext_vector_type(4)));   // MFMA C/D

__device__ __forceinline__ float b2f(u16 u) {
    unsigned v = ((unsigned)u) << 16;
    return __builtin_bit_cast(float, v);
}
__device__ __forceinline__ u16 f2b(float f) {   // RNE
    unsigned u = __builtin_bit_cast(unsigned, f);
    u += 0x7fffu + ((u >> 16) & 1u);
    return (u16)(u >> 16);
}
__device__ __forceinline__ unsigned pk2(float a, float b) {
#if __has_builtin(__builtin_amdgcn_cvt_pk_bf16_f32)
    auto r = __builtin_amdgcn_cvt_pk_bf16_f32(a, b);
    return __builtin_bit_cast(unsigned, r);
#else
    return (unsigned)f2b(a) | ((unsigned)f2b(b) << 16);
#endif
}
__device__ __forceinline__ float fexp2(float x) {
#if __has_builtin(__builtin_amdgcn_exp2f)
    return __builtin_amdgcn_exp2f(x);
#else
    return exp2f(x);
#endif
}
// async global->LDS, 16B/lane; LDS dest = wave-uniform base + lane*16
__device__ __forceinline__ void gload_lds16(const void* g, void* l) {
    __builtin_amdgcn_global_load_lds(
        (const __attribute__((address_space(1))) unsigned int*)g,
        (__attribute__((address_space(3))) unsigned int*)l, 16, 0, 0);
}

// ---------------------------------------------------------------------------
// Fused prep: fp32->bf16 convert of x (blocks 0..3071), W^T transposes for
// qkv_w (blocks 3072..3503) and proj_w (blocks 3504..3647).
// ---------------------------------------------------------------------------
__global__ __launch_bounds__(256)
void prep_kernel(const float* __restrict__ x,
                 const float* __restrict__ qkv_w,
                 const float* __restrict__ proj_w,
                 u16* __restrict__ xb,
                 u16* __restrict__ qwt,
                 u16* __restrict__ pwt) {
    __shared__ float T[64][65];
    const int t = threadIdx.x;
    if (blockIdx.x < 3072) {
        const int i = (blockIdx.x * 256 + t) * 4;
        const float4 v = *(const float4*)(x + i);
        uint2 o = { pk2(v.x, v.y), pk2(v.z, v.w) };
        *(uint2*)(xb + i) = o;
        return;
    }
    const float* W; u16* Wt; int K, N, k0, n0;
    if (blockIdx.x < 3072 + 432) {
        const int bx = blockIdx.x - 3072;      // grid (36 n-tiles, 12 k-tiles)
        W = qkv_w; Wt = qwt; K = C_; N = QKVC;
        n0 = (bx % 36) * 64; k0 = (bx / 36) * 64;
    } else {
        const int bx = blockIdx.x - 3504;      // grid (12, 12)
        W = proj_w; Wt = pwt; K = C_; N = C_;
        n0 = (bx % 12) * 64; k0 = (bx / 12) * 64;
    }
    const int r = t >> 6, c = t & 63;
#pragma unroll
    for (int p = 0; p < 16; ++p) {
        const int kl = p * 4 + r;
        T[kl][c] = W[(size_t)(k0 + kl) * N + n0 + c];
    }
    __syncthreads();
#pragma unroll
    for (int p = 0; p < 16; ++p) {
        const int nl = p * 4 + r;
        Wt[(size_t)(n0 + nl) * K + k0 + c] = f2b(T[c][nl]);
    }
}

// ---------------------------------------------------------------------------
// bf16 TN GEMM: C[M][N] = A[M][K] @ Bt[N][K]^T + bias (128x128 tile, 4 waves)
// ---------------------------------------------------------------------------
template <bool BF16OUT>
__global__ __launch_bounds__(256)
void gemm_tn_kernel(const u16* __restrict__ A, const u16* __restrict__ Bt,
                    const float* __restrict__ bias, void* __restrict__ Cout,
                    int M, int N, int K) {
    __shared__ __attribute__((aligned(16))) u16 As[128 * 32];
    __shared__ __attribute__((aligned(16))) u16 Bs[128 * 32];
    const int tid = threadIdx.x;
    const int w = tid >> 6, l = tid & 63;
    const int lq = l & 15, quad = l >> 4;
    const int mbase = blockIdx.y * 128, nbase = blockIdx.x * 128;

    f32x4 acc[4][4];
    const f32x4 z4 = {0.f, 0.f, 0.f, 0.f};
#pragma unroll
    for (int mb = 0; mb < 4; ++mb)
#pragma unroll
        for (int nb = 0; nb < 4; ++nb) acc[mb][nb] = z4;

    const int srow = (l >> 2);
    const int sdc  = (l & 3) ^ ((l >> 2) & 3);

    for (int k0 = 0; k0 < K; k0 += 32) {
#pragma unroll
        for (int cc = 0; cc < 2; ++cc) {
            const int c = 2 * w + cc;
            const int row = 16 * c + srow;
            gload_lds16(A  + (size_t)(mbase + row) * K + k0 + sdc * 8, &As[c * 512]);
            gload_lds16(Bt + (size_t)(nbase + row) * K + k0 + sdc * 8, &Bs[c * 512]);
        }
        __syncthreads();

        bf16x8 af[4], bfr[4];
#pragma unroll
        for (int mb = 0; mb < 4; ++mb)
            af[mb] = *(const bf16x8*)
                &As[((w >> 1) * 64 + mb * 16 + lq) * 32 + ((quad ^ (lq & 3)) * 8)];
#pragma unroll
        for (int nb = 0; nb < 4; ++nb)
            bfr[nb] = *(const bf16x8*)
                &Bs[((w & 1) * 64 + nb * 16 + lq) * 32 + ((quad ^ (lq & 3)) * 8)];
#pragma unroll
        for (int mb = 0; mb < 4; ++mb)
#pragma unroll
            for (int nb = 0; nb < 4; ++nb)
                acc[mb][nb] = __builtin_amdgcn_mfma_f32_16x16x32_bf16(
                    af[mb], bfr[nb], acc[mb][nb], 0, 0, 0);
        __syncthreads();
    }

#pragma unroll
    for (int nb = 0; nb < 4; ++nb) {
        const int col = nbase + (w & 1) * 64 + nb * 16 + lq;
        const float bv = bias[col];
#pragma unroll
        for (int mb = 0; mb < 4; ++mb) {
#pragma unroll
            for (int r = 0; r < 4; ++r) {
                const int row = mbase + (w >> 1) * 64 + mb * 16 + quad * 4 + r;
                const float v = acc[mb][nb][r] + bv;
                if (BF16OUT) ((u16*)Cout)[(size_t)row * N + col] = f2b(v);
                else         ((float*)Cout)[(size_t)row * N + col] = v;
            }
        }
    }
}

// ---------------------------------------------------------------------------
// 64x64-tile ONE-WAVE bf16 TN GEMM (fp32 out). For the proj GEMM: grid
// (N/64, M/64) = (12, 64) = 768 blocks = 3 blocks/CU (vs 0.75 with 128-tile).
// Same staging/fragment/swizzle pattern as gemm_tn, single wave, 16 MFMA/iter.
// ---------------------------------------------------------------------------
__global__ __launch_bounds__(64)
void gemm_tn64_kernel(const u16* __restrict__ A, const u16* __restrict__ Bt,
                      const float* __restrict__ bias, float* __restrict__ Cout,
                      int M, int N, int K) {
    __shared__ __attribute__((aligned(16))) u16 As[64 * 32];
    __shared__ __attribute__((aligned(16))) u16 Bs[64 * 32];
    const int l = threadIdx.x;
    const int lq = l & 15, quad = l >> 4;
    const int mbase = blockIdx.y * 64, nbase = blockIdx.x * 64;

    f32x4 acc[4][4];
    const f32x4 z4 = {0.f, 0.f, 0.f, 0.f};
#pragma unroll
    for (int mb = 0; mb < 4; ++mb)
#pragma unroll
        for (int nb = 0; nb < 4; ++nb) acc[mb][nb] = z4;

    const int srow = (l >> 2);
    const int sdc  = (l & 3) ^ ((l >> 2) & 3);

    for (int k0 = 0; k0 < K; k0 += 32) {
#pragma unroll
        for (int c = 0; c < 4; ++c) {
            const int row = 16 * c + srow;
            gload_lds16(A  + (size_t)(mbase + row) * K + k0 + sdc * 8, &As[c * 512]);
            gload_lds16(Bt + (size_t)(nbase + row) * K + k0 + sdc * 8, &Bs[c * 512]);
        }
        __syncthreads();   // single-wave barrier: forces vmcnt drain for LDS reads

        bf16x8 af[4], bfr[4];
#pragma unroll
        for (int mb = 0; mb < 4; ++mb)
            af[mb] = *(const bf16x8*)
                &As[(mb * 16 + lq) * 32 + ((quad ^ (lq & 3)) * 8)];
#pragma unroll
        for (int nb = 0; nb < 4; ++nb)
            bfr[nb] = *(const bf16x8*)
                &Bs[(nb * 16 + lq) * 32 + ((quad ^ (lq & 3)) * 8)];
#pragma unroll
        for (int mb = 0; mb < 4; ++mb)
#pragma unroll
            for (int nb = 0; nb < 4; ++nb)
                acc[mb][nb] = __builtin_amdgcn_mfma_f32_16x16x32_bf16(
                    af[mb], bfr[nb], acc[mb][nb], 0, 0, 0);
        __syncthreads();
    }

#pragma unroll
    for (int nb = 0; nb < 4; ++nb) {
        const int col = nbase + nb * 16 + lq;
        const float bv = bias[col];
#pragma unroll
        for (int mb = 0; mb < 4; ++mb) {
#pragma unroll
            for (int r = 0; r < 4; ++r) {
                const int row = mbase + mb * 16 + quad * 4 + r;
                Cout[(size_t)row * N + col] = acc[mb][nb][r] + bv;
            }
        }
    }
}

// ---------------------------------------------------------------------------
// RMSNorm + RoPE in-place on bf16 qkv. 16 lanes per (row,h), ushort4/lane.
// q scaled by SCALE*LOG2E. Both q and k written back CONTIGUOUSLY (kpack
// fragment-scatter moved to kvpack_kernel — R8's 8B-granule scatter killed
// write coalescing).
// ---------------------------------------------------------------------------
__global__ __launch_bounds__(256)
void normrope_kernel(u16* __restrict__ qkv,
                     const float* __restrict__ cosb,
                     const float* __restrict__ sinb,
                     const float* __restrict__ qw,
                     const float* __restrict__ kw) {
    const int item = blockIdx.x * 16 + (threadIdx.x >> 4); // (b*N+n)*H + h
    const int lq   = threadIdx.x & 15;
    const int h    = item % H_;
    const int row  = item / H_;        // b*N + n
    const int n    = row & (N_ - 1);
    const size_t base = (size_t)row * QKVC + h * HD_ + lq * 4;

    const ushort4 q4 = *(const ushort4*)&qkv[base];
    const ushort4 k4 = *(const ushort4*)&qkv[base + C_];
    float qf[4], kf[4];
    qf[0] = b2f(q4.x); qf[1] = b2f(q4.y); qf[2] = b2f(q4.z); qf[3] = b2f(q4.w);
    kf[0] = b2f(k4.x); kf[1] = b2f(k4.y); kf[2] = b2f(k4.z); kf[3] = b2f(k4.w);

    float q2 = qf[0]*qf[0] + qf[1]*qf[1] + qf[2]*qf[2] + qf[3]*qf[3];
    float k2 = kf[0]*kf[0] + kf[1]*kf[1] + kf[2]*kf[2] + kf[3]*kf[3];
#pragma unroll
    for (int off = 8; off >= 1; off >>= 1) {
        q2 += __shfl_xor(q2, off, 64);
        k2 += __shfl_xor(k2, off, 64);
    }
    const float rq = rsqrtf(q2 * (1.f / 64.f) + EPSV);
    const float rk = rsqrtf(k2 * (1.f / 64.f) + EPSV);

    const float4 qwv = *(const float4*)&qw[lq * 4];
    const float4 kwv = *(const float4*)&kw[lq * 4];
    const float4 cv  = *(const float4*)&cosb[n * HD_ + lq * 4];
    const float4 sv  = *(const float4*)&sinb[n * HD_ + lq * 4];

    float qn[4], kn[4];
    qn[0] = qf[0]*rq*qwv.x; qn[1] = qf[1]*rq*qwv.y;
    qn[2] = qf[2]*rq*qwv.z; qn[3] = qf[3]*rq*qwv.w;
    kn[0] = kf[0]*rk*kwv.x; kn[1] = kf[1]*rk*kwv.y;
    kn[2] = kf[2]*rk*kwv.z; kn[3] = kf[3]*rk*kwv.w;

    const float sgn = (lq < 8) ? -1.f : 1.f;   // partner = lq^8 (d +/- 32)
    float qo[4], ko[4];
    const float cc[4] = {cv.x, cv.y, cv.z, cv.w};
    const float ss[4] = {sv.x, sv.y, sv.z, sv.w};
#pragma unroll
    for (int j = 0; j < 4; ++j) {
        const float qp = __shfl_xor(qn[j], 8, 64);
        const float kp = __shfl_xor(kn[j], 8, 64);
        qo[j] = (qn[j] * cc[j] + sgn * qp * ss[j]) * (SCALE * LOG2E);
        ko[j] =  kn[j] * cc[j] + sgn * kp * ss[j];
    }
    uint2 qout = { pk2(qo[0], qo[1]), pk2(qo[2], qo[3]) };
    uint2 kout = { pk2(ko[0], ko[1]), pk2(ko[2], ko[3]) };
    *(uint2*)&qkv[base]      = qout;
    *(uint2*)&qkv[base + C_] = kout;
}

// ---------------------------------------------------------------------------
// K+V fragment pack, fully coalesced. One block per (bh, kt) = 768 blocks.
// Reads roped K rows + V rows (coalesced), LDS transpose, writes both packed
// tiles with 32 B/thread contiguous stores.
//   kpack elem ((kb*2+ks)*64 + l)*8 + j = K[key=kb*16+(l&15)][d=ks*32+(l>>4)*8+j]
//   vpack elem ((mb*2+ks)*64 + l)*8 + j = V[key=ks*32+(l>>4)*8+j][dv=mb*16+(l&15)]
// ---------------------------------------------------------------------------
__global__ __launch_bounds__(256)
void kvpack_kernel(const u16* __restrict__ qkv,
                   u16* __restrict__ kpack, u16* __restrict__ vpack) {
    __shared__ u16 Tk[64][72];
    __shared__ u16 Tv[64][72];
    const int kt = blockIdx.x & 31, bh = blockIdx.x >> 5;
    const int b = bh / H_, h = bh % H_;
    const int t = threadIdx.x;
    {
        const int r = t >> 2, seg = t & 3;   // row=key, 16 u16 per thread
        const u16* srck = &qkv[(size_t)(b * N_ + kt * 64 + r) * QKVC
                               + C_ + h * HD_ + seg * 16];
        *(uint4*)&Tk[r][seg * 16]     = *(const uint4*)srck;
        *(uint4*)&Tk[r][seg * 16 + 8] = *(const uint4*)(srck + 8);
        const u16* srcv = srck + C_;
        *(uint4*)&Tv[r][seg * 16]     = *(const uint4*)srcv;
        *(uint4*)&Tv[r][seg * 16 + 8] = *(const uint4*)(srcv + 8);
    }
    __syncthreads();
    const size_t tile = ((size_t)bh * 32 + kt) * 4096;
    u16 ktmp[16], vtmp[16];
#pragma unroll
    for (int g2 = 0; g2 < 2; ++g2) {
        const int g = t * 2 + g2;            // frag-chunk index 0..511
        const int blk = g >> 6;              // (kb*2+ks) / (mb*2+ks)
        const int l  = g & 63;
        const int bb = blk >> 1, ks = blk & 1;
        const int m  = l & 15,  quad = l >> 4;
#pragma unroll
        for (int j = 0; j < 8; ++j) {
            ktmp[g2 * 8 + j] = Tk[bb * 16 + m][ks * 32 + quad * 8 + j];
            vtmp[g2 * 8 + j] = Tv[ks * 32 + quad * 8 + j][bb * 16 + m];
        }
    }
    u16* kd = &kpack[tile + t * 16];
    *(uint4*)kd       = *(const uint4*)&ktmp[0];
    *(uint4*)(kd + 8) = *(const uint4*)&ktmp[8];
    u16* vd = &vpack[tile + t * 16];
    *(uint4*)vd       = *(const uint4*)&vtmp[0];
    *(uint4*)(vd + 8) = *(const uint4*)&vtmp[8];
}

// ---------------------------------------------------------------------------
// MFMA flash attention, cross-block key split (proven R8 structure) + lsum
// via ones-row MFMA: A-frag = (row0 == all-ones) constant -> lacc[nq][0] on
// quad-0 lanes accumulates sum_k P[q][k] (8 extra MFMA/iter replaces 48 VALU
// adds + 2 end shfls; denominator now consistent with the bf16 P used in PV).
// Block = 128 thr = 2 waves, same 64 queries (nq=4); kh key-half per block;
// grid 1536. launch_bounds(128,2): VGPR+AGPR ~200 < 256 cap, no spill.
// ---------------------------------------------------------------------------
__global__ __launch_bounds__(128, 2)
void flash_mfma_kernel(const u16* __restrict__ qkv,
                       const u16* __restrict__ kpack,
                       const u16* __restrict__ vpack,
                       u16* __restrict__ opart,
                       float* __restrict__ lpart) {
    __shared__ __attribute__((aligned(16))) u16 Ps[2][64 * 64];  // 16 KB
    __shared__ float lex[64];
    float* Oex = (float*)&Ps[0][0];   // overlays Ps after final barrier

    const int tid = threadIdx.x;
    const int w = tid >> 6, l = tid & 63;
    const int lq = l & 15, quad = l >> 4;
    const int sw = lq & 7;

    // XCD-pinned remap: xcd = lin&7 owns bh {3x..3x+2}; per bh: 32 qt x 2 kh.
    const int lin  = blockIdx.x;                    // 0..1535
    const int slot = lin >> 3;                      // 0..191
    const int bh   = (lin & 7) * 3 + (slot >> 6);   // 0..23
    const int rem  = slot & 63;
    const int qt   = rem >> 1;                      // 0..31
    const int kh   = rem & 1;                       // key half
    const int b = bh / H_, h = bh % H_;
    const size_t qbase = (size_t)b * N_ * QKVC + h * HD_;
    const size_t tbase = (size_t)bh * 32 * 4096;

    // ones-row A fragment: A[0][k]=1, rows 1..15 = 0  (lanes with lq==0)
    bf16x8 onesf;
    {
        const short one = (short)0x3F80;
        const short v = (lq == 0) ? one : (short)0;
#pragma unroll
        for (int j = 0; j < 8; ++j) onesf[j] = v;
    }

    // Q B-frags (both waves: same 64 queries)
    bf16x8 qb[4][2];
#pragma unroll
    for (int nq = 0; nq < 4; ++nq)
#pragma unroll
        for (int ks = 0; ks < 2; ++ks)
            qb[nq][ks] = *(const bf16x8*)
                &qkv[qbase + (size_t)(qt * 64 + nq * 16 + lq) * QKVC
                     + ks * 32 + quad * 8];

    f32x4 oacc[4][4], lacc[4];
    const f32x4 z4 = {0.f, 0.f, 0.f, 0.f};
#pragma unroll
    for (int mb = 0; mb < 4; ++mb)
#pragma unroll
        for (int nq = 0; nq < 4; ++nq) oacc[mb][nq] = z4;
#pragma unroll
    for (int nq = 0; nq < 4; ++nq) lacc[nq] = z4;

    // preload K frags for first key tile (kt = kh*16 + w)
    bf16x8 ka[4][2];
#pragma unroll
    for (int kb = 0; kb < 4; ++kb)
#pragma unroll
        for (int ks = 0; ks < 2; ++ks)
            ka[kb][ks] = *(const bf16x8*)
                &kpack[tbase + (size_t)(kh * 16 + w) * 4096
                       + ((kb * 2 + ks) * 64 + l) * 8];

    for (int kt2 = 0; kt2 < 8; ++kt2) {
        const int kt  = kh * 16 + 2 * kt2 + w;
        const int ktn = kh * 16 + ((2 * kt2 + 2 + w) & 15);  // wrap harmless
        const size_t vb   = tbase + (size_t)kt * 4096;
        const size_t kb_n = tbase + (size_t)ktn * 4096;

        // V frags — issued early, consumed at PV below
        bf16x8 va[4][2];
#pragma unroll
        for (int mb = 0; mb < 4; ++mb)
#pragma unroll
            for (int ks = 0; ks < 2; ++ks)
                va[mb][ks] = *(const bf16x8*)
                    &vpack[vb + ((mb * 2 + ks) * 64 + l) * 8];

        // per-kb: S-MFMAs -> exp2 -> P-write
#pragma unroll
        for (int kb = 0; kb < 4; ++kb) {
            f32x4 sacc[4];
#pragma unroll
            for (int nq = 0; nq < 4; ++nq) sacc[nq] = z4;
#pragma unroll
            for (int ks = 0; ks < 2; ++ks)
#pragma unroll
                for (int nq = 0; nq < 4; ++nq)
                    sacc[nq] = __builtin_amdgcn_mfma_f32_16x16x32_bf16(
                        ka[kb][ks], qb[nq][ks], sacc[nq], 0, 0, 0);
#pragma unroll
            for (int nq = 0; nq < 4; ++nq) {
                float p[4];
#pragma unroll
                for (int r = 0; r < 4; ++r) p[r] = fexp2(sacc[nq][r] - SMAX);
                uint2 pkv = { pk2(p[0], p[1]), pk2(p[2], p[3]) };
                *(uint2*)&Ps[w][(nq * 16 + lq) * 64
                                + (((kb * 2 + (quad >> 1)) ^ sw) * 8)
                                + (quad & 1) * 4] = pkv;
            }
        }

        // prefetch next K tile IN-PLACE (after all S-MFMAs consumed ka)
#pragma unroll
        for (int kb = 0; kb < 4; ++kb)
#pragma unroll
            for (int ks = 0; ks < 2; ++ks)
                ka[kb][ks] = *(const bf16x8*)
                    &kpack[kb_n + ((kb * 2 + ks) * 64 + l) * 8];

        // P B-frags (same-wave LDS RAW: DS-pipe ordered, no barrier)
        bf16x8 pb[2][4];
#pragma unroll
        for (int ks = 0; ks < 2; ++ks)
#pragma unroll
            for (int nq = 0; nq < 4; ++nq)
                pb[ks][nq] = *(const bf16x8*)
                    &Ps[w][(nq * 16 + lq) * 64 + (((ks * 4 + quad) ^ sw) * 8)];

        // O^T += V^T.P^T ;  l += ones.P^T
#pragma unroll
        for (int mb = 0; mb < 4; ++mb)
#pragma unroll
            for (int ks = 0; ks < 2; ++ks)
#pragma unroll
                for (int nq = 0; nq < 4; ++nq)
                    oacc[mb][nq] = __builtin_amdgcn_mfma_f32_16x16x32_bf16(
                        va[mb][ks], pb[ks][nq], oacc[mb][nq], 0, 0, 0);
#pragma unroll
        for (int ks = 0; ks < 2; ++ks)
#pragma unroll
            for (int nq = 0; nq < 4; ++nq)
                lacc[nq] = __builtin_amdgcn_mfma_f32_16x16x32_bf16(
                    onesf, pb[ks][nq], lacc[nq], 0, 0, 0);
    }

    // lacc[nq][0] on quad==0 lanes = sum_k P[q][k] for q = nq*16+lq

    __syncthreads();   // all Ps reads complete before Oex overlays Ps
    if (w == 1) {
#pragma unroll
        for (int nq = 0; nq < 4; ++nq) {
#pragma unroll
            for (int mb = 0; mb < 4; ++mb) {
                const int chunkS = (mb * 4 + quad) ^ lq;   // float4-chunk swizzle
                float4 v;
                v.x = oacc[mb][nq][0]; v.y = oacc[mb][nq][1];
                v.z = oacc[mb][nq][2]; v.w = oacc[mb][nq][3];
                *(float4*)&Oex[(nq * 16 + lq) * 64 + chunkS * 4] = v;
            }
            if (quad == 0) lex[nq * 16 + lq] = lacc[nq][0];
        }
    }
    __syncthreads();
    if (w == 0) {
#pragma unroll
        for (int nq = 0; nq < 4; ++nq) {
#pragma unroll
            for (int mb = 0; mb < 4; ++mb) {
                const int chunkS = (mb * 4 + quad) ^ lq;
                float4* p = (float4*)&Oex[(nq * 16 + lq) * 64 + chunkS * 4];
                float4 v = *p;
                v.x += oacc[mb][nq][0]; v.y += oacc[mb][nq][1];
                v.z += oacc[mb][nq][2]; v.w += oacc[mb][nq][3];
                *p = v;
            }
            if (quad == 0) lex[nq * 16 + lq] += lacc[nq][0];
        }
    }
    __syncthreads();

    // cooperative partial store: O (bf16, [q][dv]) + l (fp32)
    const size_t pbase_o = ((size_t)(bh * 32 + qt) * 2 + kh) * 4096;
    const size_t pbase_l = ((size_t)(bh * 32 + qt) * 2 + kh) * 64;
#pragma unroll
    for (int pass = 0; pass < 8; ++pass) {
        const int row = pass * 8 + (tid >> 4);       // q 0..63
        const int c   = tid & 15;                    // logical float4 chunk
        const int phys = c ^ (row & 15);
        const float4 v = *(const float4*)&Oex[row * 64 + phys * 4];
        uint2 o2 = { pk2(v.x, v.y), pk2(v.z, v.w) };
        *(uint2*)&opart[pbase_o + row * 64 + c * 4] = o2;
    }
    if (tid < 64) lpart[pbase_l + tid] = lex[tid];
}

// ---------------------------------------------------------------------------
// Combine the two key-half partials: attn = (O0 + O1) / (l0 + l1).
// ---------------------------------------------------------------------------
__global__ __launch_bounds__(256)
void combine_kernel(const u16* __restrict__ opart,
                    const float* __restrict__ lpart,
                    u16* __restrict__ attnb) {
    const int lin  = blockIdx.x;                    // 0..767
    const int slot = lin >> 3;                      // 0..95
    const int bh   = (lin & 7) * 3 + (slot >> 5);
    const int qt   = slot & 31;
    const int b = bh / H_, h = bh % H_;
    const int t = threadIdx.x;
    const int q = t >> 2, g = t & 3;                // q 0..63, 16-dv group

    const size_t pair = (size_t)(bh * 32 + qt) * 2;
    const float lv = lpart[pair * 64 + q] + lpart[(pair + 1) * 64 + q];
    const float inv = 1.f / lv;

    const size_t p0 = pair * 4096 + q * 64 + g * 16;
    const size_t p1 = p0 + 4096;

    u16 res[16];
#pragma unroll
    for (int j4 = 0; j4 < 4; ++j4) {
        const ushort4 a = *(const ushort4*)&opart[p0 + j4 * 4];
        const ushort4 c = *(const ushort4*)&opart[p1 + j4 * 4];
        const float v0 = (b2f(a.x) + b2f(c.x)) * inv;
        const float v1 = (b2f(a.y) + b2f(c.y)) * inv;
        const float v2 = (b2f(a.z) + b2f(c.z)) * inv;
        const float v3 = (b2f(a.w) + b2f(c.w)) * inv;
        uint2 o2 = { pk2(v0, v1), pk2(v2, v3) };
        *(uint2*)&res[j4 * 4] = o2;
    }
    u16* dst = &attnb[(size_t)(b * N_ + qt * 64 + q) * C_ + h * HD_ + g * 16];
    *(uint4*)dst       = *(const uint4*)&res[0];
    *(uint4*)(dst + 8) = *(const uint4*)&res[8];
}

// ---------------------------------------------------------------------------
extern "C" void kernel_launch(void* const* d_in, const int* in_sizes, int n_in,
                              void* d_out, int out_size, void* d_ws, size_t ws_size,
                              hipStream_t stream) {
    const float* x        = (const float*)d_in[0];
    const float* rope_cos = (const float*)d_in[1];
    const float* rope_sin = (const float*)d_in[2];
    const float* qkv_w    = (const float*)d_in[3];
    const float* qkv_b    = (const float*)d_in[4];
    const float* proj_w   = (const float*)d_in[5];
    const float* proj_b   = (const float*)d_in[6];
    const float* q_nw     = (const float*)d_in[7];
    const float* k_nw     = (const float*)d_in[8];
    float* out = (float*)d_out;

    // ws layout (~61 MB of ~256 MB). kpackb ALIASES xb (xb dead after gemm1).
    u16* xb     = (u16*)d_ws;                               // 4096x768
    u16* qwt    = xb     + (size_t)NROWS * C_;              // 2304x768 (W^T)
    u16* pwt    = qwt    + (size_t)QKVC * C_;               // 768x768  (W^T)
    u16* qkvb   = pwt    + (size_t)C_ * C_;                 // 4096x2304
    u16* vpackb = qkvb   + (size_t)NROWS * QKVC;            // 24x32x4096
    u16* attnb  = vpackb + (size_t)B_ * H_ * 32 * 4096;     // 4096x768
    u16* opartb = attnb  + (size_t)NROWS * C_;              // 1536x4096 bf16
    float* lpartb = (float*)(opartb + (size_t)1536 * 4096); // 1536x64 fp32
    u16* kpackb = xb;                                       // 24x32x4096 (alias)

    prep_kernel<<<dim3(3072 + 432 + 144), 256, 0, stream>>>(
        x, qkv_w, proj_w, xb, qwt, pwt);

    gemm_tn_kernel<true><<<dim3(QKVC / 128, NROWS / 128), 256, 0, stream>>>(
        xb, qwt, qkv_b, qkvb, NROWS, QKVC, C_);

    normrope_kernel<<<dim3(3072), 256, 0, stream>>>(
        qkvb, rope_cos, rope_sin, q_nw, k_nw);

    kvpack_kernel<<<dim3(768), 256, 0, stream>>>(qkvb, kpackb, vpackb);

    flash_mfma_kernel<<<dim3(1536), 128, 0, stream>>>(
        qkvb, kpackb, vpackb, opartb, lpartb);

    combine_kernel<<<dim3(768), 256, 0, stream>>>(opartb, lpartb, attnb);

    gemm_tn64_kernel<<<dim3(C_ / 64, NROWS / 64), 64, 0, stream>>>(
        attnb, pwt, proj_b, out, NROWS, C_, C_);
}

// Round 10
// 199.309 us; speedup vs baseline: 1.0482x; 1.0482x over previous
//
#include <hip/hip_runtime.h>
#include <math.h>

#define B_    2
#define N_    2048
#define C_    768
#define H_    12
#define HD_   64
#define NROWS (B_*N_)      // 4096
#define QKVC  (3*C_)       // 2304
#define EPSV  1e-6f
#define SCALE 0.125f       // 1/sqrt(HD)
#define LOG2E 1.44269504088896f
#define SMAX  12.0f        // static softmax max: logit*log2e <= 8*1.443+eps < 12

typedef unsigned short u16;
typedef short bf16x8 __attribute__((ext_vector_type(8)));   // 8 bf16 = 4 VGPRs
typedef float f32x4  __attribute__((ext_vector_type(4)));   // MFMA C/D

__device__ __forceinline__ float b2f(u16 u) {
    unsigned v = ((unsigned)u) << 16;
    return __builtin_bit_cast(float, v);
}
__device__ __forceinline__ u16 f2b(float f) {   // RNE
    unsigned u = __builtin_bit_cast(unsigned, f);
    u += 0x7fffu + ((u >> 16) & 1u);
    return (u16)(u >> 16);
}
__device__ __forceinline__ unsigned pk2(float a, float b) {
#if __has_builtin(__builtin_amdgcn_cvt_pk_bf16_f32)
    auto r = __builtin_amdgcn_cvt_pk_bf16_f32(a, b);
    return __builtin_bit_cast(unsigned, r);
#else
    return (unsigned)f2b(a) | ((unsigned)f2b(b) << 16);
#endif
}
__device__ __forceinline__ float fexp2(float x) {
#if __has_builtin(__builtin_amdgcn_exp2f)
    return __builtin_amdgcn_exp2f(x);
#else
    return exp2f(x);
#endif
}
// async global->LDS, 16B/lane; LDS dest = wave-uniform base + lane*16
__device__ __forceinline__ void gload_lds16(const void* g, void* l) {
    __builtin_amdgcn_global_load_lds(
        (const __attribute__((address_space(1))) unsigned int*)g,
        (__attribute__((address_space(3))) unsigned int*)l, 16, 0, 0);
}

// ---------------------------------------------------------------------------
// Fused prep: fp32->bf16 convert of x (blocks 0..3071), W^T transposes for
// qkv_w (blocks 3072..3503) and proj_w (blocks 3504..3647).
// ---------------------------------------------------------------------------
__global__ __launch_bounds__(256)
void prep_kernel(const float* __restrict__ x,
                 const float* __restrict__ qkv_w,
                 const float* __restrict__ proj_w,
                 u16* __restrict__ xb,
                 u16* __restrict__ qwt,
                 u16* __restrict__ pwt) {
    __shared__ float T[64][65];
    const int t = threadIdx.x;
    if (blockIdx.x < 3072) {
        const int i = (blockIdx.x * 256 + t) * 4;
        const float4 v = *(const float4*)(x + i);
        uint2 o = { pk2(v.x, v.y), pk2(v.z, v.w) };
        *(uint2*)(xb + i) = o;
        return;
    }
    const float* W; u16* Wt; int K, N, k0, n0;
    if (blockIdx.x < 3072 + 432) {
        const int bx = blockIdx.x - 3072;      // grid (36 n-tiles, 12 k-tiles)
        W = qkv_w; Wt = qwt; K = C_; N = QKVC;
        n0 = (bx % 36) * 64; k0 = (bx / 36) * 64;
    } else {
        const int bx = blockIdx.x - 3504;      // grid (12, 12)
        W = proj_w; Wt = pwt; K = C_; N = C_;
        n0 = (bx % 12) * 64; k0 = (bx / 12) * 64;
    }
    const int r = t >> 6, c = t & 63;
#pragma unroll
    for (int p = 0; p < 16; ++p) {
        const int kl = p * 4 + r;
        T[kl][c] = W[(size_t)(k0 + kl) * N + n0 + c];
    }
    __syncthreads();
#pragma unroll
    for (int p = 0; p < 16; ++p) {
        const int nl = p * 4 + r;
        Wt[(size_t)(n0 + nl) * K + k0 + c] = f2b(T[c][nl]);
    }
}

// ---------------------------------------------------------------------------
// bf16 TN GEMM: C[M][N] = A[M][K] @ Bt[N][K]^T + bias (128x128 tile, 4 waves)
// ---------------------------------------------------------------------------
template <bool BF16OUT>
__global__ __launch_bounds__(256)
void gemm_tn_kernel(const u16* __restrict__ A, const u16* __restrict__ Bt,
                    const float* __restrict__ bias, void* __restrict__ Cout,
                    int M, int N, int K) {
    __shared__ __attribute__((aligned(16))) u16 As[128 * 32];
    __shared__ __attribute__((aligned(16))) u16 Bs[128 * 32];
    const int tid = threadIdx.x;
    const int w = tid >> 6, l = tid & 63;
    const int lq = l & 15, quad = l >> 4;
    const int mbase = blockIdx.y * 128, nbase = blockIdx.x * 128;

    f32x4 acc[4][4];
    const f32x4 z4 = {0.f, 0.f, 0.f, 0.f};
#pragma unroll
    for (int mb = 0; mb < 4; ++mb)
#pragma unroll
        for (int nb = 0; nb < 4; ++nb) acc[mb][nb] = z4;

    const int srow = (l >> 2);
    const int sdc  = (l & 3) ^ ((l >> 2) & 3);

    for (int k0 = 0; k0 < K; k0 += 32) {
#pragma unroll
        for (int cc = 0; cc < 2; ++cc) {
            const int c = 2 * w + cc;
            const int row = 16 * c + srow;
            gload_lds16(A  + (size_t)(mbase + row) * K + k0 + sdc * 8, &As[c * 512]);
            gload_lds16(Bt + (size_t)(nbase + row) * K + k0 + sdc * 8, &Bs[c * 512]);
        }
        __syncthreads();

        bf16x8 af[4], bfr[4];
#pragma unroll
        for (int mb = 0; mb < 4; ++mb)
            af[mb] = *(const bf16x8*)
                &As[((w >> 1) * 64 + mb * 16 + lq) * 32 + ((quad ^ (lq & 3)) * 8)];
#pragma unroll
        for (int nb = 0; nb < 4; ++nb)
            bfr[nb] = *(const bf16x8*)
                &Bs[((w & 1) * 64 + nb * 16 + lq) * 32 + ((quad ^ (lq & 3)) * 8)];
#pragma unroll
        for (int mb = 0; mb < 4; ++mb)
#pragma unroll
            for (int nb = 0; nb < 4; ++nb)
                acc[mb][nb] = __builtin_amdgcn_mfma_f32_16x16x32_bf16(
                    af[mb], bfr[nb], acc[mb][nb], 0, 0, 0);
        __syncthreads();
    }

#pragma unroll
    for (int nb = 0; nb < 4; ++nb) {
        const int col = nbase + (w & 1) * 64 + nb * 16 + lq;
        const float bv = bias[col];
#pragma unroll
        for (int mb = 0; mb < 4; ++mb) {
#pragma unroll
            for (int r = 0; r < 4; ++r) {
                const int row = mbase + (w >> 1) * 64 + mb * 16 + quad * 4 + r;
                const float v = acc[mb][nb][r] + bv;
                if (BF16OUT) ((u16*)Cout)[(size_t)row * N + col] = f2b(v);
                else         ((float*)Cout)[(size_t)row * N + col] = v;
            }
        }
    }
}

// ---------------------------------------------------------------------------
// 64x64-tile ONE-WAVE bf16 TN GEMM (fp32 out). Proj GEMM: grid (12,64)=768
// blocks = 3 blocks/CU.
// ---------------------------------------------------------------------------
__global__ __launch_bounds__(64)
void gemm_tn64_kernel(const u16* __restrict__ A, const u16* __restrict__ Bt,
                      const float* __restrict__ bias, float* __restrict__ Cout,
                      int M, int N, int K) {
    __shared__ __attribute__((aligned(16))) u16 As[64 * 32];
    __shared__ __attribute__((aligned(16))) u16 Bs[64 * 32];
    const int l = threadIdx.x;
    const int lq = l & 15, quad = l >> 4;
    const int mbase = blockIdx.y * 64, nbase = blockIdx.x * 64;

    f32x4 acc[4][4];
    const f32x4 z4 = {0.f, 0.f, 0.f, 0.f};
#pragma unroll
    for (int mb = 0; mb < 4; ++mb)
#pragma unroll
        for (int nb = 0; nb < 4; ++nb) acc[mb][nb] = z4;

    const int srow = (l >> 2);
    const int sdc  = (l & 3) ^ ((l >> 2) & 3);

    for (int k0 = 0; k0 < K; k0 += 32) {
#pragma unroll
        for (int c = 0; c < 4; ++c) {
            const int row = 16 * c + srow;
            gload_lds16(A  + (size_t)(mbase + row) * K + k0 + sdc * 8, &As[c * 512]);
            gload_lds16(Bt + (size_t)(nbase + row) * K + k0 + sdc * 8, &Bs[c * 512]);
        }
        __syncthreads();

        bf16x8 af[4], bfr[4];
#pragma unroll
        for (int mb = 0; mb < 4; ++mb)
            af[mb] = *(const bf16x8*)
                &As[(mb * 16 + lq) * 32 + ((quad ^ (lq & 3)) * 8)];
#pragma unroll
        for (int nb = 0; nb < 4; ++nb)
            bfr[nb] = *(const bf16x8*)
                &Bs[(nb * 16 + lq) * 32 + ((quad ^ (lq & 3)) * 8)];
#pragma unroll
        for (int mb = 0; mb < 4; ++mb)
#pragma unroll
            for (int nb = 0; nb < 4; ++nb)
                acc[mb][nb] = __builtin_amdgcn_mfma_f32_16x16x32_bf16(
                    af[mb], bfr[nb], acc[mb][nb], 0, 0, 0);
        __syncthreads();
    }

#pragma unroll
    for (int nb = 0; nb < 4; ++nb) {
        const int col = nbase + nb * 16 + lq;
        const float bv = bias[col];
#pragma unroll
        for (int mb = 0; mb < 4; ++mb) {
#pragma unroll
            for (int r = 0; r < 4; ++r) {
                const int row = mbase + mb * 16 + quad * 4 + r;
                Cout[(size_t)row * N + col] = acc[mb][nb][r] + bv;
            }
        }
    }
}

// ---------------------------------------------------------------------------
// RMSNorm + RoPE in-place on bf16 qkv. 16 lanes per (row,h), ushort4/lane.
// q scaled by SCALE*LOG2E; q and k written back contiguously.
// ---------------------------------------------------------------------------
__global__ __launch_bounds__(256)
void normrope_kernel(u16* __restrict__ qkv,
                     const float* __restrict__ cosb,
                     const float* __restrict__ sinb,
                     const float* __restrict__ qw,
                     const float* __restrict__ kw) {
    const int item = blockIdx.x * 16 + (threadIdx.x >> 4); // (b*N+n)*H + h
    const int lq   = threadIdx.x & 15;
    const int h    = item % H_;
    const int row  = item / H_;        // b*N + n
    const int n    = row & (N_ - 1);
    const size_t base = (size_t)row * QKVC + h * HD_ + lq * 4;

    const ushort4 q4 = *(const ushort4*)&qkv[base];
    const ushort4 k4 = *(const ushort4*)&qkv[base + C_];
    float qf[4], kf[4];
    qf[0] = b2f(q4.x); qf[1] = b2f(q4.y); qf[2] = b2f(q4.z); qf[3] = b2f(q4.w);
    kf[0] = b2f(k4.x); kf[1] = b2f(k4.y); kf[2] = b2f(k4.z); kf[3] = b2f(k4.w);

    float q2 = qf[0]*qf[0] + qf[1]*qf[1] + qf[2]*qf[2] + qf[3]*qf[3];
    float k2 = kf[0]*kf[0] + kf[1]*kf[1] + kf[2]*kf[2] + kf[3]*kf[3];
#pragma unroll
    for (int off = 8; off >= 1; off >>= 1) {
        q2 += __shfl_xor(q2, off, 64);
        k2 += __shfl_xor(k2, off, 64);
    }
    const float rq = rsqrtf(q2 * (1.f / 64.f) + EPSV);
    const float rk = rsqrtf(k2 * (1.f / 64.f) + EPSV);

    const float4 qwv = *(const float4*)&qw[lq * 4];
    const float4 kwv = *(const float4*)&kw[lq * 4];
    const float4 cv  = *(const float4*)&cosb[n * HD_ + lq * 4];
    const float4 sv  = *(const float4*)&sinb[n * HD_ + lq * 4];

    float qn[4], kn[4];
    qn[0] = qf[0]*rq*qwv.x; qn[1] = qf[1]*rq*qwv.y;
    qn[2] = qf[2]*rq*qwv.z; qn[3] = qf[3]*rq*qwv.w;
    kn[0] = kf[0]*rk*kwv.x; kn[1] = kf[1]*rk*kwv.y;
    kn[2] = kf[2]*rk*kwv.z; kn[3] = kf[3]*rk*kwv.w;

    const float sgn = (lq < 8) ? -1.f : 1.f;   // partner = lq^8 (d +/- 32)
    float qo[4], ko[4];
    const float cc[4] = {cv.x, cv.y, cv.z, cv.w};
    const float ss[4] = {sv.x, sv.y, sv.z, sv.w};
#pragma unroll
    for (int j = 0; j < 4; ++j) {
        const float qp = __shfl_xor(qn[j], 8, 64);
        const float kp = __shfl_xor(kn[j], 8, 64);
        qo[j] = (qn[j] * cc[j] + sgn * qp * ss[j]) * (SCALE * LOG2E);
        ko[j] =  kn[j] * cc[j] + sgn * kp * ss[j];
    }
    uint2 qout = { pk2(qo[0], qo[1]), pk2(qo[2], qo[3]) };
    uint2 kout = { pk2(ko[0], ko[1]), pk2(ko[2], ko[3]) };
    *(uint2*)&qkv[base]      = qout;
    *(uint2*)&qkv[base + C_] = kout;
}

// ---------------------------------------------------------------------------
// K+V fragment pack, fully coalesced. One block per (bh, kt) = 768 blocks.
// ---------------------------------------------------------------------------
__global__ __launch_bounds__(256)
void kvpack_kernel(const u16* __restrict__ qkv,
                   u16* __restrict__ kpack, u16* __restrict__ vpack) {
    __shared__ u16 Tk[64][72];
    __shared__ u16 Tv[64][72];
    const int kt = blockIdx.x & 31, bh = blockIdx.x >> 5;
    const int b = bh / H_, h = bh % H_;
    const int t = threadIdx.x;
    {
        const int r = t >> 2, seg = t & 3;   // row=key, 16 u16 per thread
        const u16* srck = &qkv[(size_t)(b * N_ + kt * 64 + r) * QKVC
                               + C_ + h * HD_ + seg * 16];
        *(uint4*)&Tk[r][seg * 16]     = *(const uint4*)srck;
        *(uint4*)&Tk[r][seg * 16 + 8] = *(const uint4*)(srck + 8);
        const u16* srcv = srck + C_;
        *(uint4*)&Tv[r][seg * 16]     = *(const uint4*)srcv;
        *(uint4*)&Tv[r][seg * 16 + 8] = *(const uint4*)(srcv + 8);
    }
    __syncthreads();
    const size_t tile = ((size_t)bh * 32 + kt) * 4096;
    u16 ktmp[16], vtmp[16];
#pragma unroll
    for (int g2 = 0; g2 < 2; ++g2) {
        const int g = t * 2 + g2;            // frag-chunk index 0..511
        const int blk = g >> 6;              // (kb*2+ks) / (mb*2+ks)
        const int l  = g & 63;
        const int bb = blk >> 1, ks = blk & 1;
        const int m  = l & 15,  quad = l >> 4;
#pragma unroll
        for (int j = 0; j < 8; ++j) {
            ktmp[g2 * 8 + j] = Tk[bb * 16 + m][ks * 32 + quad * 8 + j];
            vtmp[g2 * 8 + j] = Tv[ks * 32 + quad * 8 + j][bb * 16 + m];
        }
    }
    u16* kd = &kpack[tile + t * 16];
    *(uint4*)kd       = *(const uint4*)&ktmp[0];
    *(uint4*)(kd + 8) = *(const uint4*)&ktmp[8];
    u16* vd = &vpack[tile + t * 16];
    *(uint4*)vd       = *(const uint4*)&vtmp[0];
    *(uint4*)(vd + 8) = *(const uint4*)&vtmp[8];
}

// ---------------------------------------------------------------------------
// MFMA flash attention, SINGLE-WAVE blocks for 3 waves/SIMD residency.
// Block = 64 thr = 1 wave; 32 queries (nq=2), key-half kh (16 kt tiles).
// Grid = 24bh x 64qt x 2kh = 3072 single-wave blocks = 12 waves/CU in ONE
// round at launch_bounds(64,3) (VGPR cap 170 — register budget engineered:
// nq=2 halves oacc to 32 AGPR; va software-pipelined per-mb (16 regs);
// no cross-iter K prefetch (3-wave overlap hides the L2 latency instead);
// lsum in VALU (R9: lsum-via-MFMA was a slight regression — reverted).
// Static-max softmax (SMAX) => additive partials; combine merges 2 halves.
// LDS: 4 KB per-wave Ps, reused for the O store transpose (same-wave DS
// ordering, no barriers anywhere). Spill signature: FETCH >> 10 MB.
// ---------------------------------------------------------------------------
__global__ __launch_bounds__(64, 3)
void flash_mfma_kernel(const u16* __restrict__ qkv,
                       const u16* __restrict__ kpack,
                       const u16* __restrict__ vpack,
                       u16* __restrict__ opart,
                       float* __restrict__ lpart) {
    __shared__ __attribute__((aligned(16))) u16 Ps[32 * 64];  // 4 KB

    const int l = threadIdx.x;
    const int lq = l & 15, quad = l >> 4;
    const int sw = lq & 7;

    // XCD-pinned remap: xcd = lin&7 owns bh {3x..3x+2}; per bh: 64 qt x 2 kh.
    const int lin  = blockIdx.x;                    // 0..3071
    const int slot = lin >> 3;                      // 0..383
    const int bh   = (lin & 7) * 3 + (slot >> 7);   // 0..23
    const int rem  = slot & 127;
    const int qt   = rem >> 1;                      // 0..63 (32-query tiles)
    const int kh   = rem & 1;                       // key half
    const int b = bh / H_, h = bh % H_;
    const size_t qbase = (size_t)b * N_ * QKVC + h * HD_;
    const size_t tbase = (size_t)bh * 32 * 4096;

    // Q B-frags (32 queries)
    bf16x8 qb[2][2];
#pragma unroll
    for (int nq = 0; nq < 2; ++nq)
#pragma unroll
        for (int ks = 0; ks < 2; ++ks)
            qb[nq][ks] = *(const bf16x8*)
                &qkv[qbase + (size_t)(qt * 32 + nq * 16 + lq) * QKVC
                     + ks * 32 + quad * 8];

    float lsum[2] = {0.f, 0.f};
    f32x4 oacc[4][2];
    const f32x4 z4 = {0.f, 0.f, 0.f, 0.f};
#pragma unroll
    for (int mb = 0; mb < 4; ++mb)
#pragma unroll
        for (int nq = 0; nq < 2; ++nq) oacc[mb][nq] = z4;

    for (int kt2 = 0; kt2 < 16; ++kt2) {
        const size_t ktile = tbase + (size_t)(kh * 16 + kt2) * 4096;

        // K frags for this tile (L2 latency hidden by 3-wave/SIMD overlap)
        bf16x8 ka[4][2];
#pragma unroll
        for (int kb = 0; kb < 4; ++kb)
#pragma unroll
            for (int ks = 0; ks < 2; ++ks)
                ka[kb][ks] = *(const bf16x8*)
                    &kpack[ktile + ((kb * 2 + ks) * 64 + l) * 8];

        // per-kb: S-MFMAs -> exp2 -> P-write
#pragma unroll
        for (int kb = 0; kb < 4; ++kb) {
            f32x4 sacc[2];
#pragma unroll
            for (int nq = 0; nq < 2; ++nq) sacc[nq] = z4;
#pragma unroll
            for (int ks = 0; ks < 2; ++ks)
#pragma unroll
                for (int nq = 0; nq < 2; ++nq)
                    sacc[nq] = __builtin_amdgcn_mfma_f32_16x16x32_bf16(
                        ka[kb][ks], qb[nq][ks], sacc[nq], 0, 0, 0);
#pragma unroll
            for (int nq = 0; nq < 2; ++nq) {
                float p[4];
#pragma unroll
                for (int r = 0; r < 4; ++r) p[r] = fexp2(sacc[nq][r] - SMAX);
                lsum[nq] += (p[0] + p[1]) + (p[2] + p[3]);
                uint2 pkv = { pk2(p[0], p[1]), pk2(p[2], p[3]) };
                *(uint2*)&Ps[(nq * 16 + lq) * 64
                             + (((kb * 2 + (quad >> 1)) ^ sw) * 8)
                             + (quad & 1) * 4] = pkv;
            }
        }

        // P B-frags (same-wave LDS RAW: DS-pipe ordered, no barrier)
        bf16x8 pb[2][2];
#pragma unroll
        for (int ks = 0; ks < 2; ++ks)
#pragma unroll
            for (int nq = 0; nq < 2; ++nq)
                pb[ks][nq] = *(const bf16x8*)
                    &Ps[(nq * 16 + lq) * 64 + (((ks * 4 + quad) ^ sw) * 8)];

        // O^T += V^T.P^T ; va software-pipelined per-mb (16 live regs)
        const size_t vtile = ktile;   // same tile index in vpack
        bf16x8 vaA[2], vaB[2];
#pragma unroll
        for (int ks = 0; ks < 2; ++ks)
            vaA[ks] = *(const bf16x8*)&vpack[vtile + ((ks) * 64 + l) * 8];
#pragma unroll
        for (int mb = 0; mb < 4; ++mb) {
            if (mb < 3) {
#pragma unroll
                for (int ks = 0; ks < 2; ++ks)
                    vaB[ks] = *(const bf16x8*)
                        &vpack[vtile + (((mb + 1) * 2 + ks) * 64 + l) * 8];
            }
#pragma unroll
            for (int ks = 0; ks < 2; ++ks)
#pragma unroll
                for (int nq = 0; nq < 2; ++nq)
                    oacc[mb][nq] = __builtin_amdgcn_mfma_f32_16x16x32_bf16(
                        vaA[ks], pb[ks][nq], oacc[mb][nq], 0, 0, 0);
#pragma unroll
            for (int ks = 0; ks < 2; ++ks) vaA[ks] = vaB[ks];
        }
    }

    // reduce l over quad groups
#pragma unroll
    for (int nq = 0; nq < 2; ++nq) {
        lsum[nq] += __shfl_xor(lsum[nq], 16, 64);
        lsum[nq] += __shfl_xor(lsum[nq], 32, 64);
    }

    // epilogue: O (bf16) -> Ps [q][dv] swizzled (same-wave, no barrier),
    // then coalesced 16B stores. 32 q x 64 dv = 4 KB.
#pragma unroll
    for (int nq = 0; nq < 2; ++nq) {
#pragma unroll
        for (int mb = 0; mb < 4; ++mb) {
            uint2 ov = { pk2(oacc[mb][nq][0], oacc[mb][nq][1]),
                         pk2(oacc[mb][nq][2], oacc[mb][nq][3]) };
            *(uint2*)&Ps[(nq * 16 + lq) * 64
                         + (((mb * 2 + (quad >> 1)) ^ sw) * 8)
                         + (quad & 1) * 4] = ov;
        }
    }
    const size_t pbase_o = ((size_t)(bh * 64 + qt) * 2 + kh) * 2048;
    const size_t pbase_l = ((size_t)(bh * 64 + qt) * 2 + kh) * 32;
#pragma unroll
    for (int pass = 0; pass < 4; ++pass) {
        const int ql = pass * 8 + (l >> 3);          // 0..31
        const int c  = l & 7;                        // dv chunk8
        const bf16x8 v = *(const bf16x8*)&Ps[ql * 64 + ((c ^ (ql & 7)) * 8)];
        *(bf16x8*)&opart[pbase_o + ql * 64 + c * 8] = v;
    }
    if (quad == 0) {
        lpart[pbase_l + lq]      = lsum[0];
        lpart[pbase_l + 16 + lq] = lsum[1];
    }
}

// ---------------------------------------------------------------------------
// Combine the two key-half partials: attn = (O0 + O1) / (l0 + l1).
// Grid 768 XCD-pinned; each block covers (bh, 64 queries = 2 qt32 tiles).
// ---------------------------------------------------------------------------
__global__ __launch_bounds__(256)
void combine_kernel(const u16* __restrict__ opart,
                    const float* __restrict__ lpart,
                    u16* __restrict__ attnb) {
    const int lin  = blockIdx.x;                    // 0..767
    const int slot = lin >> 3;                      // 0..95
    const int bh   = (lin & 7) * 3 + (slot >> 5);
    const int qt   = slot & 31;                     // 64-query group
    const int b = bh / H_, h = bh % H_;
    const int t = threadIdx.x;
    const int q = t >> 2, g = t & 3;                // q 0..63, 16-dv group

    const int tile32 = qt * 2 + (q >> 5);           // 32-q tile 0..63
    const int r32    = q & 31;
    const size_t p0  = ((size_t)(bh * 64 + tile32) * 2);

    const float lv = lpart[p0 * 32 + r32] + lpart[p0 * 32 + 32 + r32];
    const float inv = 1.f / lv;

    const size_t o0 = p0 * 2048 + r32 * 64 + g * 16;
    const size_t o1 = o0 + 2048;

    u16 res[16];
#pragma unroll
    for (int j4 = 0; j4 < 4; ++j4) {
        const ushort4 a = *(const ushort4*)&opart[o0 + j4 * 4];
        const ushort4 c = *(const ushort4*)&opart[o1 + j4 * 4];
        const float v0 = (b2f(a.x) + b2f(c.x)) * inv;
        const float v1 = (b2f(a.y) + b2f(c.y)) * inv;
        const float v2 = (b2f(a.z) + b2f(c.z)) * inv;
        const float v3 = (b2f(a.w) + b2f(c.w)) * inv;
        uint2 o2 = { pk2(v0, v1), pk2(v2, v3) };
        *(uint2*)&res[j4 * 4] = o2;
    }
    u16* dst = &attnb[(size_t)(b * N_ + qt * 64 + q) * C_ + h * HD_ + g * 16];
    *(uint4*)dst       = *(const uint4*)&res[0];
    *(uint4*)(dst + 8) = *(const uint4*)&res[8];
}

// ---------------------------------------------------------------------------
extern "C" void kernel_launch(void* const* d_in, const int* in_sizes, int n_in,
                              void* d_out, int out_size, void* d_ws, size_t ws_size,
                              hipStream_t stream) {
    const float* x        = (const float*)d_in[0];
    const float* rope_cos = (const float*)d_in[1];
    const float* rope_sin = (const float*)d_in[2];
    const float* qkv_w    = (const float*)d_in[3];
    const float* qkv_b    = (const float*)d_in[4];
    const float* proj_w   = (const float*)d_in[5];
    const float* proj_b   = (const float*)d_in[6];
    const float* q_nw     = (const float*)d_in[7];
    const float* k_nw     = (const float*)d_in[8];
    float* out = (float*)d_out;

    // ws layout (~61 MB of ~256 MB). kpackb ALIASES xb (xb dead after gemm1).
    u16* xb     = (u16*)d_ws;                               // 4096x768
    u16* qwt    = xb     + (size_t)NROWS * C_;              // 2304x768 (W^T)
    u16* pwt    = qwt    + (size_t)QKVC * C_;               // 768x768  (W^T)
    u16* qkvb   = pwt    + (size_t)C_ * C_;                 // 4096x2304
    u16* vpackb = qkvb   + (size_t)NROWS * QKVC;            // 24x32x4096
    u16* attnb  = vpackb + (size_t)B_ * H_ * 32 * 4096;     // 4096x768
    u16* opartb = attnb  + (size_t)NROWS * C_;              // 6144x2048 bf16
    float* lpartb = (float*)(opartb + (size_t)6144 * 2048); // 6144x32 fp32
    u16* kpackb = xb;                                       // 24x32x4096 (alias)

    prep_kernel<<<dim3(3072 + 432 + 144), 256, 0, stream>>>(
        x, qkv_w, proj_w, xb, qwt, pwt);

    gemm_tn_kernel<true><<<dim3(QKVC / 128, NROWS / 128), 256, 0, stream>>>(
        xb, qwt, qkv_b, qkvb, NROWS, QKVC, C_);

    normrope_kernel<<<dim3(3072), 256, 0, stream>>>(
        qkvb, rope_cos, rope_sin, q_nw, k_nw);

    kvpack_kernel<<<dim3(768), 256, 0, stream>>>(qkvb, kpackb, vpackb);

    flash_mfma_kernel<<<dim3(3072), 64, 0, stream>>>(
        qkvb, kpackb, vpackb, opartb, lpartb);

    combine_kernel<<<dim3(768), 256, 0, stream>>>(opartb, lpartb, attnb);

    gemm_tn64_kernel<<<dim3(C_ / 64, NROWS / 64), 64, 0, stream>>>(
        attnb, pwt, proj_b, out, NROWS, C_, C_);
}